// Round 16
// baseline (178.298 us; speedup 1.0000x reference)
//
#include <hip/hip_runtime.h>
#include <math.h>

#define SEQ 2048
#define NTOK 4096
#define DM 1024

typedef __bf16 bf16x8 __attribute__((ext_vector_type(8)));
typedef __bf16 bf16x4 __attribute__((ext_vector_type(4)));
typedef float  f32x4  __attribute__((ext_vector_type(4)));

__device__ __forceinline__ void gll16(const void* g, void* l) {
    __builtin_amdgcn_global_load_lds(
        (const __attribute__((address_space(1))) void*)g,
        (__attribute__((address_space(3))) void*)l, 16, 0, 0);
}

__device__ __forceinline__ f32x4 mfma16(bf16x8 a, bf16x8 b, f32x4 c) {
    return __builtin_amdgcn_mfma_f32_16x16x32_bf16(a, b, c, 0, 0, 0);
}

// ---------------------------------------------------------------------------
// merged fp32->bf16 conversion for hs + 4 weights, PLUS RoPE tables.
// wq pre-scaled by 0.125 (pow2 -> exact in bf16).
// ---------------------------------------------------------------------------
__global__ void conv_all(const float* __restrict__ hs, const float* __restrict__ wq,
                         const float* __restrict__ wk, const float* __restrict__ wv,
                         const float* __restrict__ wo, __bf16* hsb, __bf16* wqb,
                         __bf16* wkb, __bf16* wvb, __bf16* wob,
                         float* __restrict__ ct, float* __restrict__ st) {
    if (blockIdx.x >= 8192) {
        int t = (blockIdx.x - 8192) * 256 + threadIdx.x;   // 0..131071
        int s = t >> 6, d = t & 63;
        int e = d & 31;
        float invf = 1.0f / powf(10000.0f, (float)e / 32.0f);
        float ang  = (float)s * invf;    // fp32 rounding as in reference
        double a   = (double)ang;
        ct[s * 64 + d] = (float)cos(a);
        st[s * 64 + d] = (float)sin(a);
        return;
    }
    long i = (long)blockIdx.x * 256 + threadIdx.x;     // 4-element units
    const long H4 = (long)NTOK * DM / 4;               // 1048576
    const float* src; __bf16* dst; long off;
    float scale = 1.0f;
    if (i < H4) { src = hs; dst = hsb; off = i; }
    else {
        long t = i - H4;
        int wsel = (int)(t >> 18);                     // W4 = 262144 = 2^18
        off = t & ((1L << 18) - 1);
        switch (wsel) {
            case 0:  src = wq; dst = wqb; scale = 0.125f; break;
            case 1:  src = wk; dst = wkb; break;
            case 2:  src = wv; dst = wvb; break;
            default: src = wo; dst = wob; break;
        }
    }
    float4 v = ((const float4*)src)[off];
    __bf16* o = dst + off * 4;
    o[0] = (__bf16)(v.x * scale); o[1] = (__bf16)(v.y * scale);
    o[2] = (__bf16)(v.z * scale); o[3] = (__bf16)(v.w * scale);
}

// ---------------------------------------------------------------------------
// C[M,N] = A[M,K=1024] @ B[N,K]^T, optional fused RoPE.
// BK=32, THREE buffers (48 KB), counted-vmcnt pipeline (proven R15).
// ---------------------------------------------------------------------------
template <typename OutT, bool ROPE>
__device__ __forceinline__ void gemm_core(__bf16* __restrict__ L,
                                          const __bf16* __restrict__ A,
                                          const __bf16* __restrict__ B,
                                          OutT* __restrict__ C, int N,
                                          const float* __restrict__ ct,
                                          const float* __restrict__ st,
                                          long bm, long bn) {
    const int tid  = threadIdx.x;
    const int lane = tid & 63;
    const int wid  = tid >> 6;
    const int l15  = lane & 15, lg = lane >> 4;
    const int wr = (wid >> 1) * 64, wc = (wid & 1) * 64;

    f32x4 acc[4][4];
    #pragma unroll
    for (int i = 0; i < 4; ++i)
        #pragma unroll
        for (int j = 0; j < 4; ++j) acc[i][j] = 0;

    const int i0 = tid, i1 = tid + 256;
    const __bf16* Ag0 = A + (bm + (i0 >> 2)) * 1024 + (((i0 & 3) ^ ((i0 >> 3) & 3)) * 8);
    const __bf16* Ag1 = A + (bm + (i1 >> 2)) * 1024 + (((i1 & 3) ^ ((i1 >> 3) & 3)) * 8);
    const __bf16* Bg0 = B + (bn + (i0 >> 2)) * 1024 + (((i0 & 3) ^ ((i0 >> 3) & 3)) * 8);
    const __bf16* Bg1 = B + (bn + (i1 >> 2)) * 1024 + (((i1 & 3) ^ ((i1 >> 3) & 3)) * 8);

    auto stage = [&](int buf, int k0) {
        gll16(Ag0 + k0, &L[buf * 8192 + tid * 8]);
        gll16(Ag1 + k0, &L[buf * 8192 + 2048 + tid * 8]);
        gll16(Bg0 + k0, &L[buf * 8192 + 4096 + tid * 8]);
        gll16(Bg1 + k0, &L[buf * 8192 + 6144 + tid * 8]);
    };

    const int rbase = l15 * 32 + ((lg ^ ((l15 >> 1) & 3)) * 8);

    auto compute = [&](int buf) {
        const int AS = buf * 8192, BS = buf * 8192 + 4096;
        bf16x8 a[4], b[4];
        #pragma unroll
        for (int i = 0; i < 4; ++i)
            a[i] = *(const bf16x8*)(L + AS + (wr + i * 16) * 32 + rbase);
        #pragma unroll
        for (int j = 0; j < 4; ++j)
            b[j] = *(const bf16x8*)(L + BS + (wc + j * 16) * 32 + rbase);
        __builtin_amdgcn_s_setprio(1);
        #pragma unroll
        for (int i = 0; i < 4; ++i)
            #pragma unroll
            for (int j = 0; j < 4; ++j)
                acc[i][j] = mfma16(a[i], b[j], acc[i][j]);
        __builtin_amdgcn_s_setprio(0);
    };

    stage(0, 0);
    stage(1, 32);

    #pragma unroll 1
    for (int tt = 0; tt < 30; tt += 3) {
        asm volatile("s_waitcnt vmcnt(4)" ::: "memory");
        __builtin_amdgcn_s_barrier();
        __builtin_amdgcn_sched_barrier(0);
        stage(2, (tt + 2) * 32); compute(0);

        asm volatile("s_waitcnt vmcnt(4)" ::: "memory");
        __builtin_amdgcn_s_barrier();
        __builtin_amdgcn_sched_barrier(0);
        stage(0, (tt + 3) * 32); compute(1);

        asm volatile("s_waitcnt vmcnt(4)" ::: "memory");
        __builtin_amdgcn_s_barrier();
        __builtin_amdgcn_sched_barrier(0);
        stage(1, (tt + 4) * 32); compute(2);
    }
    asm volatile("s_waitcnt vmcnt(4)" ::: "memory");
    __builtin_amdgcn_s_barrier();
    __builtin_amdgcn_sched_barrier(0);
    compute(0);
    asm volatile("s_waitcnt vmcnt(0)" ::: "memory");
    __builtin_amdgcn_s_barrier();
    __builtin_amdgcn_sched_barrier(0);
    compute(1);

    if constexpr (ROPE) {
        #pragma unroll
        for (int i = 0; i < 4; ++i)
            #pragma unroll
            for (int j = 0; j < 2; ++j)
                #pragma unroll
                for (int r = 0; r < 4; ++r) {
                    long row = bm + wr + i * 16 + lg * 4 + r;
                    int  s   = (int)(row & (SEQ - 1));
                    int  d   = j * 16 + l15;
                    float c  = ct[s * 64 + d];
                    float sn = st[s * 64 + d];
                    float x0 = acc[i][j][r], x1 = acc[i][j + 2][r];
                    long col = bn + wc + j * 16 + l15;
                    C[row * N + col]      = (OutT)(x0 * c - x1 * sn);
                    C[row * N + col + 32] = (OutT)(x1 * c + x0 * sn);
                }
    } else {
        #pragma unroll
        for (int i = 0; i < 4; ++i)
            #pragma unroll
            for (int j = 0; j < 4; ++j)
                #pragma unroll
                for (int r = 0; r < 4; ++r) {
                    long row = bm + wr + i * 16 + lg * 4 + r;
                    long col = bn + wc + j * 16 + l15;
                    C[row * N + col] = (OutT)acc[i][j][r];
                }
    }
}

// merged Q+K+V^T projections, XCD-aware 1D grid (768 blocks)
__global__ __launch_bounds__(256) void gemm_qkv(const __bf16* __restrict__ hsb,
                                                const __bf16* __restrict__ wqb,
                                                const __bf16* __restrict__ wkb,
                                                const __bf16* __restrict__ wvb,
                                                __bf16* __restrict__ Qb,
                                                __bf16* __restrict__ Kb,
                                                __bf16* __restrict__ Vtb,
                                                const float* __restrict__ ct,
                                                const float* __restrict__ st) {
    __shared__ __bf16 L[24576];   // 48 KB, shared by all template paths
    const int bid = blockIdx.x;
    const int w = (bid & 7) * 96 + (bid >> 3);   // XCD-contiguous work id
    const int z = w >> 8, rem = w & 255;
    if (z < 2)   // Q (wq pre-scaled by 0.125) and K, RoPE fused
        gemm_core<__bf16, true>(L, hsb, z ? wkb : wqb, z ? Kb : Qb, 1024, ct, st,
                                (long)(rem >> 3) * 128, (long)(rem & 7) * 128);
    else
        gemm_core<__bf16, false>(L, wvb, hsb, Vtb, 4096, nullptr, nullptr,
                                 (long)(rem & 7) * 128, (long)(rem >> 3) * 128);
}

// out-projection, XCD-aware 1D grid (256 blocks)
__global__ __launch_bounds__(256) void gemm_out(const __bf16* __restrict__ A,
                                                const __bf16* __restrict__ B,
                                                float* __restrict__ C) {
    __shared__ __bf16 L[24576];
    const int bid = blockIdx.x;
    const int w = (bid & 7) * 32 + (bid >> 3);
    gemm_core<float, false>(L, A, B, C, 1024, nullptr, nullptr,
                            (long)(w >> 3) * 128, (long)(w & 7) * 128);
}

// ---------------------------------------------------------------------------
// Flash attention v13 = v9 arithmetic with K/V read DIRECTLY from global
// (L2-resident: 256 KB per (h,b) slice, pinned to one XCD by grid order).
// The LDS granule swizzle algebra collapses: lane (l15,lg)'s fragment is
// plain K[row][h*64 + lg*8] / V^T[d][.. + wk*32 + lg*8]. No staging, no
// main-loop barriers (P bounce is wave-private) -> waves free-run.
// LDS 37.4 KB: P @0 (128x64 bf16), epilogue f32 dump overlays it.
// ---------------------------------------------------------------------------
#define FIXED_M 16.0f

__global__ __launch_bounds__(512) void flash13(const __bf16* __restrict__ Qb,
                                               const __bf16* __restrict__ Kb,
                                               const __bf16* __restrict__ Vt,
                                               __bf16* __restrict__ Ob) {
    __shared__ __bf16 L[18688];   // 37376 B
    const int h = blockIdx.x, b = blockIdx.y, qt = blockIdx.z;
    const int tid = threadIdx.x, lane = tid & 63, w = tid >> 6;   // w 0..7
    const int wq = w >> 1, wk = w & 1;
    const int l15 = lane & 15, lg = lane >> 4;
    const int x7  = l15 & 7;

    // P bounce bases (LDS, wave-private; swizzled for bank spread)
    const int prb = (wq * 32 + l15) * 64 + (((wk * 4 + lg) ^ x7) * 8); // + qa*1024
    int wb[2];
    #pragma unroll
    for (int j = 0; j < 2; ++j)
        wb[j] = (wq * 32 + l15) * 64 +
                (((wk * 4 + j * 2 + (lg >> 1)) ^ x7) * 8) + (lg & 1) * 4;

    // Q B-fragments (2 q-groups), loaded once (Q pre-scaled by 0.125)
    bf16x8 qf[2][2];
    #pragma unroll
    for (int qa = 0; qa < 2; ++qa) {
        long qrow = (long)b * SEQ + qt * 128 + wq * 32 + qa * 16 + l15;
        qf[qa][0] = *(const bf16x8*)(Qb + qrow * DM + h * 64 + lg * 8);
        qf[qa][1] = *(const bf16x8*)(Qb + qrow * DM + h * 64 + 32 + lg * 8);
    }

    f32x4 oacc[2][4];
    #pragma unroll
    for (int qa = 0; qa < 2; ++qa)
        #pragma unroll
        for (int i = 0; i < 4; ++i) oacc[qa][i] = 0;
    f32x4 lvec[2] = {0, 0};

    // per-lane global fragment pointers (advanced by 64 rows / 64 cols per iter)
    const __bf16* kg = Kb + ((long)b * SEQ + wk * 32 + l15) * DM + h * 64 + lg * 8;
    const __bf16* vg = Vt + ((long)h * 64 + l15) * NTOK + (long)b * SEQ
                          + wk * 32 + lg * 8;

    const float L2E = 1.4426950408889634f;
    const float mL  = FIXED_M * L2E;

    #pragma unroll 1
    for (int t = 0; t < 32; ++t) {
        // issue all 8 fragment loads up front (V results needed only post-softmax)
        bf16x8 ka[2][2], va[4];
        #pragma unroll
        for (int j = 0; j < 2; ++j) {
            ka[j][0] = *(const bf16x8*)(kg + (long)(j * 16) * DM);
            ka[j][1] = *(const bf16x8*)(kg + (long)(j * 16) * DM + 32);
        }
        #pragma unroll
        for (int i = 0; i < 4; ++i)
            va[i] = *(const bf16x8*)(vg + (long)(i * 16) * NTOK);
        kg += (long)64 * DM;
        vg += 64;

        // QK^T (swapped, k-half wk): sc[qa][j] = S^T[k=wk*32+j*16+lg*4+r][q=l15]
        f32x4 sc[2][2];
        __builtin_amdgcn_s_setprio(1);
        #pragma unroll
        for (int j = 0; j < 2; ++j)
            #pragma unroll
            for (int qa = 0; qa < 2; ++qa) {
                f32x4 z = 0;
                z = mfma16(ka[j][0], qf[qa][0], z);
                z = mfma16(ka[j][1], qf[qa][1], z);
                sc[qa][j] = z;
            }
        __builtin_amdgcn_s_setprio(0);

        // p = exp2(s*log2e - M*log2e); per-lane sums; P -> LDS (wave-private)
        #pragma unroll
        for (int qa = 0; qa < 2; ++qa) {
            f32x4 rv = 0;
            #pragma unroll
            for (int j = 0; j < 2; ++j) {
                #pragma unroll
                for (int r = 0; r < 4; ++r)
                    sc[qa][j][r] = __builtin_amdgcn_exp2f(
                        __builtin_fmaf(sc[qa][j][r], L2E, -mL));
                rv += sc[qa][j];
            }
            lvec[qa] += rv;
            #pragma unroll
            for (int j = 0; j < 2; ++j) {
                bf16x4 p4;
                p4[0] = (__bf16)sc[qa][j][0]; p4[1] = (__bf16)sc[qa][j][1];
                p4[2] = (__bf16)sc[qa][j][2]; p4[3] = (__bf16)sc[qa][j][3];
                *(bf16x4*)(L + wb[j] + qa * 1024) = p4;
            }
        }

        // PV on this wave's k-half: O^T[d][q] += V^T[d][k] * P^T[k][q]
        bf16x8 pb[2];
        #pragma unroll
        for (int qa = 0; qa < 2; ++qa)
            pb[qa] = *(const bf16x8*)(L + prb + qa * 1024);
        __builtin_amdgcn_s_setprio(1);
        #pragma unroll
        for (int i = 0; i < 4; ++i)
            #pragma unroll
            for (int qa = 0; qa < 2; ++qa)
                oacc[qa][i] = mfma16(va[i], pb[qa], oacc[qa][i]);
        __builtin_amdgcn_s_setprio(0);
    }

    // ---- cross-wave (wk) combine of partial l and O^T ----
    float lh[2];
    #pragma unroll
    for (int qa = 0; qa < 2; ++qa) {
        float l = (lvec[qa][0] + lvec[qa][1]) + (lvec[qa][2] + lvec[qa][3]);
        l += __shfl_xor(l, 16);
        l += __shfl_xor(l, 32);
        lh[qa] = l;
    }

    __syncthreads();                 // all P reads done before LDS reuse
    float* df = (float*)L;           // oacc dump: stride 36 floats (bank-spread)
    float* lf = df + 9216;           // l dump: 128 floats
    if (wk) {
        const int base = (wq * 64 + lane) * 36;
        #pragma unroll
        for (int qa = 0; qa < 2; ++qa) {
            #pragma unroll
            for (int i = 0; i < 4; ++i)
                *(f32x4*)(df + base + qa * 16 + i * 4) = oacc[qa][i];
            if (lg == 0) lf[wq * 32 + qa * 16 + l15] = lh[qa];
        }
    }
    __syncthreads();
    if (!wk) {
        const int base = (wq * 64 + lane) * 36;
        #pragma unroll
        for (int qa = 0; qa < 2; ++qa) {
            float lt = lh[qa] + lf[wq * 32 + qa * 16 + l15];
            float linv = 1.0f / lt;
            const long tok = (long)b * SEQ + qt * 128 + wq * 32 + qa * 16 + l15;
            #pragma unroll
            for (int i = 0; i < 4; ++i) {
                f32x4 ot = oacc[qa][i] + *(const f32x4*)(df + base + qa * 16 + i * 4);
                bf16x4 o4;
                #pragma unroll
                for (int r = 0; r < 4; ++r) o4[r] = (__bf16)(ot[r] * linv);
                *(bf16x4*)(Ob + tok * DM + h * 64 + i * 16 + lg * 4) = o4;
            }
        }
    }
}

// ---------------------------------------------------------------------------
extern "C" void kernel_launch(void* const* d_in, const int* in_sizes, int n_in,
                              void* d_out, int out_size, void* d_ws, size_t ws_size,
                              hipStream_t stream) {
    const float* hs = (const float*)d_in[0];
    const float* wq = (const float*)d_in[1];
    const float* wk = (const float*)d_in[2];
    const float* wv = (const float*)d_in[3];
    const float* wo = (const float*)d_in[4];
    float* out = (float*)d_out;

    __bf16* hsb = (__bf16*)d_ws;
    __bf16* wqb = hsb + (long)NTOK * DM;
    __bf16* wkb = wqb + DM * DM;
    __bf16* wvb = wkb + DM * DM;
    __bf16* wob = wvb + DM * DM;
    __bf16* Qb  = wob + DM * DM;                 // attn out aliases Qb (disjoint)
    __bf16* Kb  = Qb + (long)NTOK * DM;
    __bf16* Vtb = Kb + (long)NTOK * DM;          // V^T: [1024][4096]
    float*  ct  = (float*)(Vtb + (long)NTOK * DM);
    float*  st  = ct + SEQ * 64;

    // converts (wq pre-scaled) + RoPE tables in one launch
    conv_all<<<dim3(8704), 256, 0, stream>>>(hs, wq, wk, wv, wo,
                                             hsb, wqb, wkb, wvb, wob, ct, st);

    // Q,K (RoPE fused) + V^T, XCD-contiguous 1D grid
    gemm_qkv<<<dim3(768), 256, 0, stream>>>(hsb, wqb, wkb, wvb,
                                            Qb, Kb, Vtb, ct, st);

    // grid (h, b, qt): qt-blocks sharing K/V land on one XCD
    flash13<<<dim3(16, 2, SEQ / 128), 512, 0, stream>>>(Qb, Kb, Vtb, Qb);

    // out = attn @ wo^T (fp32 out), XCD-contiguous 1D grid
    gemm_out<<<dim3(256), 256, 0, stream>>>(Qb, wob, out);
}

// Round 17
// 106.127 us; speedup vs baseline: 1.6800x; 1.6800x over previous
//
#include <hip/hip_runtime.h>
#include <math.h>

#define SEQ 2048
#define NTOK 4096
#define DM 1024

typedef __bf16 bf16x8 __attribute__((ext_vector_type(8)));
typedef __bf16 bf16x4 __attribute__((ext_vector_type(4)));
typedef float  f32x4  __attribute__((ext_vector_type(4)));

__device__ __forceinline__ void gll16(const void* g, void* l) {
    __builtin_amdgcn_global_load_lds(
        (const __attribute__((address_space(1))) void*)g,
        (__attribute__((address_space(3))) void*)l, 16, 0, 0);
}

__device__ __forceinline__ f32x4 mfma16(bf16x8 a, bf16x8 b, f32x4 c) {
    return __builtin_amdgcn_mfma_f32_16x16x32_bf16(a, b, c, 0, 0, 0);
}

// ---------------------------------------------------------------------------
// merged fp32->bf16 conversion for hs + 4 weights, PLUS RoPE tables.
// wq pre-scaled by 0.125 (pow2 -> exact in bf16).
// ---------------------------------------------------------------------------
__global__ void conv_all(const float* __restrict__ hs, const float* __restrict__ wq,
                         const float* __restrict__ wk, const float* __restrict__ wv,
                         const float* __restrict__ wo, __bf16* hsb, __bf16* wqb,
                         __bf16* wkb, __bf16* wvb, __bf16* wob,
                         float* __restrict__ ct, float* __restrict__ st) {
    if (blockIdx.x >= 8192) {
        int t = (blockIdx.x - 8192) * 256 + threadIdx.x;   // 0..131071
        int s = t >> 6, d = t & 63;
        int e = d & 31;
        float invf = 1.0f / powf(10000.0f, (float)e / 32.0f);
        float ang  = (float)s * invf;    // fp32 rounding as in reference
        double a   = (double)ang;
        ct[s * 64 + d] = (float)cos(a);
        st[s * 64 + d] = (float)sin(a);
        return;
    }
    long i = (long)blockIdx.x * 256 + threadIdx.x;     // 4-element units
    const long H4 = (long)NTOK * DM / 4;               // 1048576
    const float* src; __bf16* dst; long off;
    float scale = 1.0f;
    if (i < H4) { src = hs; dst = hsb; off = i; }
    else {
        long t = i - H4;
        int wsel = (int)(t >> 18);                     // W4 = 262144 = 2^18
        off = t & ((1L << 18) - 1);
        switch (wsel) {
            case 0:  src = wq; dst = wqb; scale = 0.125f; break;
            case 1:  src = wk; dst = wkb; break;
            case 2:  src = wv; dst = wvb; break;
            default: src = wo; dst = wob; break;
        }
    }
    float4 v = ((const float4*)src)[off];
    __bf16* o = dst + off * 4;
    o[0] = (__bf16)(v.x * scale); o[1] = (__bf16)(v.y * scale);
    o[2] = (__bf16)(v.z * scale); o[3] = (__bf16)(v.w * scale);
}

// ---------------------------------------------------------------------------
// C[M,N] = A[M,K=1024] @ B[N,K]^T, optional fused RoPE.
// BK=32, THREE buffers (48 KB), counted-vmcnt pipeline (proven R15).
// ---------------------------------------------------------------------------
template <typename OutT, bool ROPE>
__device__ __forceinline__ void gemm_core(__bf16* __restrict__ L,
                                          const __bf16* __restrict__ A,
                                          const __bf16* __restrict__ B,
                                          OutT* __restrict__ C, int N,
                                          const float* __restrict__ ct,
                                          const float* __restrict__ st,
                                          long bm, long bn) {
    const int tid  = threadIdx.x;
    const int lane = tid & 63;
    const int wid  = tid >> 6;
    const int l15  = lane & 15, lg = lane >> 4;
    const int wr = (wid >> 1) * 64, wc = (wid & 1) * 64;

    f32x4 acc[4][4];
    #pragma unroll
    for (int i = 0; i < 4; ++i)
        #pragma unroll
        for (int j = 0; j < 4; ++j) acc[i][j] = 0;

    const int i0 = tid, i1 = tid + 256;
    const __bf16* Ag0 = A + (bm + (i0 >> 2)) * 1024 + (((i0 & 3) ^ ((i0 >> 3) & 3)) * 8);
    const __bf16* Ag1 = A + (bm + (i1 >> 2)) * 1024 + (((i1 & 3) ^ ((i1 >> 3) & 3)) * 8);
    const __bf16* Bg0 = B + (bn + (i0 >> 2)) * 1024 + (((i0 & 3) ^ ((i0 >> 3) & 3)) * 8);
    const __bf16* Bg1 = B + (bn + (i1 >> 2)) * 1024 + (((i1 & 3) ^ ((i1 >> 3) & 3)) * 8);

    auto stage = [&](int buf, int k0) {
        gll16(Ag0 + k0, &L[buf * 8192 + tid * 8]);
        gll16(Ag1 + k0, &L[buf * 8192 + 2048 + tid * 8]);
        gll16(Bg0 + k0, &L[buf * 8192 + 4096 + tid * 8]);
        gll16(Bg1 + k0, &L[buf * 8192 + 6144 + tid * 8]);
    };

    const int rbase = l15 * 32 + ((lg ^ ((l15 >> 1) & 3)) * 8);

    auto compute = [&](int buf) {
        const int AS = buf * 8192, BS = buf * 8192 + 4096;
        bf16x8 a[4], b[4];
        #pragma unroll
        for (int i = 0; i < 4; ++i)
            a[i] = *(const bf16x8*)(L + AS + (wr + i * 16) * 32 + rbase);
        #pragma unroll
        for (int j = 0; j < 4; ++j)
            b[j] = *(const bf16x8*)(L + BS + (wc + j * 16) * 32 + rbase);
        __builtin_amdgcn_s_setprio(1);
        #pragma unroll
        for (int i = 0; i < 4; ++i)
            #pragma unroll
            for (int j = 0; j < 4; ++j)
                acc[i][j] = mfma16(a[i], b[j], acc[i][j]);
        __builtin_amdgcn_s_setprio(0);
    };

    stage(0, 0);
    stage(1, 32);

    #pragma unroll 1
    for (int tt = 0; tt < 30; tt += 3) {
        asm volatile("s_waitcnt vmcnt(4)" ::: "memory");
        __builtin_amdgcn_s_barrier();
        __builtin_amdgcn_sched_barrier(0);
        stage(2, (tt + 2) * 32); compute(0);

        asm volatile("s_waitcnt vmcnt(4)" ::: "memory");
        __builtin_amdgcn_s_barrier();
        __builtin_amdgcn_sched_barrier(0);
        stage(0, (tt + 3) * 32); compute(1);

        asm volatile("s_waitcnt vmcnt(4)" ::: "memory");
        __builtin_amdgcn_s_barrier();
        __builtin_amdgcn_sched_barrier(0);
        stage(1, (tt + 4) * 32); compute(2);
    }
    asm volatile("s_waitcnt vmcnt(4)" ::: "memory");
    __builtin_amdgcn_s_barrier();
    __builtin_amdgcn_sched_barrier(0);
    compute(0);
    asm volatile("s_waitcnt vmcnt(0)" ::: "memory");
    __builtin_amdgcn_s_barrier();
    __builtin_amdgcn_sched_barrier(0);
    compute(1);

    if constexpr (ROPE) {
        #pragma unroll
        for (int i = 0; i < 4; ++i)
            #pragma unroll
            for (int j = 0; j < 2; ++j)
                #pragma unroll
                for (int r = 0; r < 4; ++r) {
                    long row = bm + wr + i * 16 + lg * 4 + r;
                    int  s   = (int)(row & (SEQ - 1));
                    int  d   = j * 16 + l15;
                    float c  = ct[s * 64 + d];
                    float sn = st[s * 64 + d];
                    float x0 = acc[i][j][r], x1 = acc[i][j + 2][r];
                    long col = bn + wc + j * 16 + l15;
                    C[row * N + col]      = (OutT)(x0 * c - x1 * sn);
                    C[row * N + col + 32] = (OutT)(x1 * c + x0 * sn);
                }
    } else {
        #pragma unroll
        for (int i = 0; i < 4; ++i)
            #pragma unroll
            for (int j = 0; j < 4; ++j)
                #pragma unroll
                for (int r = 0; r < 4; ++r) {
                    long row = bm + wr + i * 16 + lg * 4 + r;
                    long col = bn + wc + j * 16 + l15;
                    C[row * N + col] = (OutT)acc[i][j][r];
                }
    }
}

// merged Q+K+V^T projections, XCD-aware 1D grid (768 blocks)
__global__ __launch_bounds__(256) void gemm_qkv(const __bf16* __restrict__ hsb,
                                                const __bf16* __restrict__ wqb,
                                                const __bf16* __restrict__ wkb,
                                                const __bf16* __restrict__ wvb,
                                                __bf16* __restrict__ Qb,
                                                __bf16* __restrict__ Kb,
                                                __bf16* __restrict__ Vtb,
                                                const float* __restrict__ ct,
                                                const float* __restrict__ st) {
    __shared__ __bf16 L[24576];   // 48 KB, shared by all template paths
    const int bid = blockIdx.x;
    const int w = (bid & 7) * 96 + (bid >> 3);   // XCD-contiguous work id
    const int z = w >> 8, rem = w & 255;
    if (z < 2)   // Q (wq pre-scaled by 0.125) and K, RoPE fused
        gemm_core<__bf16, true>(L, hsb, z ? wkb : wqb, z ? Kb : Qb, 1024, ct, st,
                                (long)(rem >> 3) * 128, (long)(rem & 7) * 128);
    else
        gemm_core<__bf16, false>(L, wvb, hsb, Vtb, 4096, nullptr, nullptr,
                                 (long)(rem & 7) * 128, (long)(rem >> 3) * 128);
}

// out-projection, XCD-aware 1D grid (256 blocks)
__global__ __launch_bounds__(256) void gemm_out(const __bf16* __restrict__ A,
                                                const __bf16* __restrict__ B,
                                                float* __restrict__ C) {
    __shared__ __bf16 L[24576];
    const int bid = blockIdx.x;
    const int w = (bid & 7) * 32 + (bid >> 3);
    gemm_core<float, false>(L, A, B, C, 1024, nullptr, nullptr,
                            (long)(w >> 3) * 128, (long)(w & 7) * 128);
}

// ---------------------------------------------------------------------------
// Flash attention v9 (proven best, 48.9 us): 8 waves as (wq 0..3, wk 0..1),
// fixed-M softmax, native exp2, setprio, XCD grid (h,b,qt), 2-buffer
// T3-minimum schedule via global_load_lds (the staging pipeline IS the
// latency-hiding engine -- direct-L2 fragment reads cost 2.6x, R16),
// 48 KB LDS -> 3 blocks/CU, stride-36 epilogue combine.
// ---------------------------------------------------------------------------
#define FIXED_M 16.0f

__global__ __launch_bounds__(512) void flash9(const __bf16* __restrict__ Qb,
                                              const __bf16* __restrict__ Kb,
                                              const __bf16* __restrict__ Vt,
                                              __bf16* __restrict__ Ob) {
    __shared__ __bf16 L[24576];   // 48 KB
    const int h = blockIdx.x, b = blockIdx.y, qt = blockIdx.z;
    const int tid = threadIdx.x, lane = tid & 63, w = tid >> 6;   // w 0..7
    const int wq = w >> 1, wk = w & 1;
    const int l15 = lane & 15, lg = lane >> 4;

    // per-lane read bases (element units), hoisted once
    const int x7  = l15 & 7;
    const int kb0 = wk * 2048 + l15 * 64 + ((lg ^ x7) * 8);        // + KS + j*1024
    const int kb1 = wk * 2048 + l15 * 64 + (((4 + lg) ^ x7) * 8);
    const int vb0 = l15 * 64 + (((wk * 4 + lg) ^ x7) * 8);         // + VS + i*1024
    const int prb = 16384 + (wq * 32 + l15) * 64 + (((wk * 4 + lg) ^ x7) * 8); // + qa*1024
    int wb[2];
    #pragma unroll
    for (int j = 0; j < 2; ++j)
        wb[j] = 16384 + (wq * 32 + l15) * 64 +
                (((wk * 4 + j * 2 + (lg >> 1)) ^ x7) * 8) + (lg & 1) * 4;

    // Q B-fragments (2 q-groups), loaded once (Q pre-scaled by 0.125)
    bf16x8 qf[2][2];
    #pragma unroll
    for (int qa = 0; qa < 2; ++qa) {
        long qrow = (long)b * SEQ + qt * 128 + wq * 32 + qa * 16 + l15;
        qf[qa][0] = *(const bf16x8*)(Qb + qrow * DM + h * 64 + lg * 8);
        qf[qa][1] = *(const bf16x8*)(Qb + qrow * DM + h * 64 + 32 + lg * 8);
    }

    f32x4 oacc[2][4];
    #pragma unroll
    for (int qa = 0; qa < 2; ++qa)
        #pragma unroll
        for (int i = 0; i < 4; ++i) oacc[qa][i] = 0;
    f32x4 lvec[2] = {0, 0};

    // staging: 512 threads cover one 64x64 K tile + one 64x64 V^T tile
    const int srow = tid >> 3;               // 0..63
    const int sgz  = (tid & 7) ^ (srow & 7);
    const __bf16* kp = Kb + ((long)b * SEQ + srow) * DM + h * 64 + sgz * 8;
    const __bf16* vp = Vt + ((long)h * 64 + srow) * NTOK + (long)b * SEQ + sgz * 8;

    auto stage = [&](int bf) {
        gll16(kp, &L[bf * 4096 + tid * 8]);
        gll16(vp, &L[8192 + bf * 4096 + tid * 8]);
        kp += (long)64 * DM;
        vp += 64;
    };

    const float L2E = 1.4426950408889634f;
    const float mL  = FIXED_M * L2E;

    auto compute = [&](int bf) {
        const int KS = bf * 4096, VS = 8192 + bf * 4096;
        f32x4 sc[2][2];
        __builtin_amdgcn_s_setprio(1);
        #pragma unroll
        for (int j = 0; j < 2; ++j) {
            bf16x8 ka0 = *(const bf16x8*)(L + KS + j * 1024 + kb0);
            bf16x8 ka1 = *(const bf16x8*)(L + KS + j * 1024 + kb1);
            #pragma unroll
            for (int qa = 0; qa < 2; ++qa) {
                f32x4 z = 0;
                z = mfma16(ka0, qf[qa][0], z);
                z = mfma16(ka1, qf[qa][1], z);
                sc[qa][j] = z;
            }
        }
        __builtin_amdgcn_s_setprio(0);

        #pragma unroll
        for (int qa = 0; qa < 2; ++qa) {
            f32x4 rv = 0;
            #pragma unroll
            for (int j = 0; j < 2; ++j) {
                #pragma unroll
                for (int r = 0; r < 4; ++r)
                    sc[qa][j][r] = __builtin_amdgcn_exp2f(
                        __builtin_fmaf(sc[qa][j][r], L2E, -mL));
                rv += sc[qa][j];
            }
            lvec[qa] += rv;
            #pragma unroll
            for (int j = 0; j < 2; ++j) {
                bf16x4 p4;
                p4[0] = (__bf16)sc[qa][j][0]; p4[1] = (__bf16)sc[qa][j][1];
                p4[2] = (__bf16)sc[qa][j][2]; p4[3] = (__bf16)sc[qa][j][3];
                *(bf16x4*)(L + wb[j] + qa * 1024) = p4;
            }
        }

        bf16x8 pb[2];
        #pragma unroll
        for (int qa = 0; qa < 2; ++qa)
            pb[qa] = *(const bf16x8*)(L + prb + qa * 1024);
        __builtin_amdgcn_s_setprio(1);
        #pragma unroll
        for (int i = 0; i < 4; ++i) {
            bf16x8 vb = *(const bf16x8*)(L + VS + i * 1024 + vb0);
            #pragma unroll
            for (int qa = 0; qa < 2; ++qa)
                oacc[qa][i] = mfma16(vb, pb[qa], oacc[qa][i]);
        }
        __builtin_amdgcn_s_setprio(0);
    };

    stage(0);                 // tile 0 -> buf0
    __syncthreads();

    #pragma unroll 1
    for (int t = 0; t < 32; t += 2) {
        stage(1);             // tile t+1 -> buf1
        compute(0);           // tile t
        __syncthreads();
        if (t + 2 < 32) stage(0);   // tile t+2 -> buf0
        compute(1);           // tile t+1
        __syncthreads();
    }

    // ---- cross-wave (wk) combine of partial l and O^T ----
    float lh[2];
    #pragma unroll
    for (int qa = 0; qa < 2; ++qa) {
        float l = (lvec[qa][0] + lvec[qa][1]) + (lvec[qa][2] + lvec[qa][3]);
        l += __shfl_xor(l, 16);
        l += __shfl_xor(l, 32);
        lh[qa] = l;
    }

    float* df = (float*)L;           // oacc dump: stride 36 floats (bank-spread)
    float* lf = df + 9216;           // l dump: 128 floats
    if (wk) {
        const int base = (wq * 64 + lane) * 36;
        #pragma unroll
        for (int qa = 0; qa < 2; ++qa) {
            #pragma unroll
            for (int i = 0; i < 4; ++i)
                *(f32x4*)(df + base + qa * 16 + i * 4) = oacc[qa][i];
            if (lg == 0) lf[wq * 32 + qa * 16 + l15] = lh[qa];
        }
    }
    __syncthreads();
    if (!wk) {
        const int base = (wq * 64 + lane) * 36;
        #pragma unroll
        for (int qa = 0; qa < 2; ++qa) {
            float lt = lh[qa] + lf[wq * 32 + qa * 16 + l15];
            float linv = 1.0f / lt;
            const long tok = (long)b * SEQ + qt * 128 + wq * 32 + qa * 16 + l15;
            #pragma unroll
            for (int i = 0; i < 4; ++i) {
                f32x4 ot = oacc[qa][i] + *(const f32x4*)(df + base + qa * 16 + i * 4);
                bf16x4 o4;
                #pragma unroll
                for (int r = 0; r < 4; ++r) o4[r] = (__bf16)(ot[r] * linv);
                *(bf16x4*)(Ob + tok * DM + h * 64 + i * 16 + lg * 4) = o4;
            }
        }
    }
}

// ---------------------------------------------------------------------------
extern "C" void kernel_launch(void* const* d_in, const int* in_sizes, int n_in,
                              void* d_out, int out_size, void* d_ws, size_t ws_size,
                              hipStream_t stream) {
    const float* hs = (const float*)d_in[0];
    const float* wq = (const float*)d_in[1];
    const float* wk = (const float*)d_in[2];
    const float* wv = (const float*)d_in[3];
    const float* wo = (const float*)d_in[4];
    float* out = (float*)d_out;

    __bf16* hsb = (__bf16*)d_ws;
    __bf16* wqb = hsb + (long)NTOK * DM;
    __bf16* wkb = wqb + DM * DM;
    __bf16* wvb = wkb + DM * DM;
    __bf16* wob = wvb + DM * DM;
    __bf16* Qb  = wob + DM * DM;                 // attn out aliases Qb (disjoint)
    __bf16* Kb  = Qb + (long)NTOK * DM;
    __bf16* Vtb = Kb + (long)NTOK * DM;          // V^T: [1024][4096]
    float*  ct  = (float*)(Vtb + (long)NTOK * DM);
    float*  st  = ct + SEQ * 64;

    // converts (wq pre-scaled) + RoPE tables in one launch
    conv_all<<<dim3(8704), 256, 0, stream>>>(hs, wq, wk, wv, wo,
                                             hsb, wqb, wkb, wvb, wob, ct, st);

    // Q,K (RoPE fused) + V^T, XCD-contiguous 1D grid
    gemm_qkv<<<dim3(768), 256, 0, stream>>>(hsb, wqb, wkb, wvb,
                                            Qb, Kb, Vtb, ct, st);

    // grid (h, b, qt): qt-blocks sharing K/V land on one XCD
    flash9<<<dim3(16, 2, SEQ / 128), 512, 0, stream>>>(Qb, Kb, Vtb, Qb);

    // out = attn @ wo^T (fp32 out), XCD-contiguous 1D grid
    gemm_out<<<dim3(256), 256, 0, stream>>>(Qb, wob, out);
}